// Round 8
// baseline (254.687 us; speedup 1.0000x reference)
//
#include <hip/hip_runtime.h>
#include <hip/hip_bf16.h>
#include <stdint.h>

// Problem: B=4, N=1024, C=768, H=12, hd=64.
// out_x = (attn(qx,kx,vx,+) + attn(qyo,kx,vx,-)) @ Wp^T + bp
// out_y = (attn(qy,ky,vx,+) + attn(qxo,ky,vx,-)) @ Wp^T + bp   (vy = vx!)
// qkv[b,n, j*768 + h*64 + d], j in {0:qo, 1:q, 2:k, 3:v}
// NOTE: w_qkv rows j=0 are pre-scaled by -0.125*log2(e), j=1 by +0.125*log2(e)
// in cvt_bf16, so attention scores emerge in the log2 domain with sign folded:
// softmax is exp2(s) directly for BOTH self and cross attends.

#define BB 4
#define NN 1024
#define CC 768
#define HH 12
#define HD 64

typedef unsigned short u16;
typedef short short8 __attribute__((ext_vector_type(8)));
typedef float f32x4 __attribute__((ext_vector_type(4)));

extern "C" __device__ float __ocml_native_exp2_f32(float);

__device__ __forceinline__ u16 f2bf(float f) {
  unsigned int u = __float_as_uint(f);
  return (u16)((u + 0x7fffu + ((u >> 16) & 1u)) >> 16);
}

__device__ __forceinline__ void load_lds16(const u16* g, u16* l) {
  __builtin_amdgcn_global_load_lds((__attribute__((address_space(1))) const void*)g,
                                   (__attribute__((address_space(3))) void*)l, 16, 0, 0);
}

// fp32 -> bf16 conversion: seg 0=x, 1=y, 2=w_qkv (query rows pre-scaled), 3=w_proj
__global__ __launch_bounds__(256)
void cvt_bf16(const float* __restrict__ x, const float* __restrict__ y,
              const float* __restrict__ wq, const float* __restrict__ wp,
              u16* __restrict__ xb, u16* __restrict__ yb,
              u16* __restrict__ wqb, u16* __restrict__ wpb)
{
  const int seg = blockIdx.y;
  const float* src = seg == 0 ? x : (seg == 1 ? y : (seg == 2 ? wq : wp));
  u16* dst = seg == 0 ? xb : (seg == 1 ? yb : (seg == 2 ? wqb : wpb));
  const int n = (seg == 3) ? 768 * 768 : ((seg == 2) ? 3072 * 768 : 4096 * 768);
  const int i = (blockIdx.x * 256 + threadIdx.x) * 8;
  if (i >= n) return;
  float sc = 1.0f;
  if (seg == 2) {
    const int row = i / 768;  // output feature p; j = p/768
    sc = (row < 768) ? -0.18033688f : (row < 1536 ? 0.18033688f : 1.0f);
  }
  float4 a = *(const float4*)(src + i);
  float4 b = *(const float4*)(src + i + 4);
  ushort4 u0 = {f2bf(a.x * sc), f2bf(a.y * sc), f2bf(a.z * sc), f2bf(a.w * sc)};
  ushort4 u1 = {f2bf(b.x * sc), f2bf(b.y * sc), f2bf(b.z * sc), f2bf(b.w * sc)};
  *(ushort4*)(dst + i) = u0;
  *(ushort4*)(dst + i + 4) = u1;
}

// V^T prepass: VT[(bh*64 + d)*1024 + key] = qkv_x[b, key, 3*768 + h*64 + d]
// 1-D grid, XCD-swizzled so producer blocks land on the XCD that consumes VT[bh].
__global__ __launch_bounds__(256)
void vtrans(const u16* __restrict__ qkvx, u16* __restrict__ VT)
{
  const int blk = blockIdx.x;                 // 1536 blocks
  const int xcd = blk & 7, slot = blk >> 3;   // 192 slots
  const int bh = (slot >> 5) * 8 + xcd;       // 6 groups x 8 = 48
  const int kt = slot & 31;                   // 32 key-tiles
  const int b = bh / HH, h = bh % HH;
  const int t = threadIdx.x;
  const int key = kt * 32 + (t >> 3), d0 = (t & 7) * 8;
  uint4 v = *(const uint4*)(qkvx + (size_t)(b * NN + key) * 3072 + 3 * CC + h * HD + d0);
  u16 e[8];
  *(uint4*)e = v;
#pragma unroll
  for (int i = 0; i < 8; i++)
    VT[(size_t)(bh * 64 + d0 + i) * 1024 + key] = e[i];
}

// MFMA GEMM: C[m,p] = A[m,:] . W[p,:] (+bias). 128x128 tile, 4 waves, BK=64.
// global_load_lds width=16 staging + XOR swizzle (chunk ^ row&7).
template<int NP, bool BF16OUT, bool BIAS>
__global__ __launch_bounds__(256)
void gemm_mfma(const u16* __restrict__ A0, const u16* __restrict__ A1,
               const u16* __restrict__ W, const float* __restrict__ bias,
               void* __restrict__ C0, void* __restrict__ C1)
{
  __shared__ u16 As[128 * 64];
  __shared__ u16 Bs[128 * 64];
  const u16* A = blockIdx.z ? A1 : A0;
  void* C = blockIdx.z ? C1 : C0;
  const int m0 = blockIdx.y * 128, n0 = blockIdx.x * 128;
  const int t = threadIdx.x, w = t >> 6, lane = t & 63;
  const int c = lane & 15, qq = lane >> 4;
  const int mq = (w >> 1) * 64, nq = (w & 1) * 64;

  const int lrow = lane >> 3;
  const int lchunk = (lane & 7) ^ lrow;
  size_t arow[4], brow[4];
#pragma unroll
  for (int i = 0; i < 4; i++) {
    const int r = (w * 4 + i) * 8 + lrow;
    arow[i] = (size_t)(m0 + r) * 768 + lchunk * 8;
    brow[i] = (size_t)(n0 + r) * 768 + lchunk * 8;
  }

  f32x4 acc[4][4] = {};
  for (int k0 = 0; k0 < 768; k0 += 64) {
    __syncthreads();
#pragma unroll
    for (int i = 0; i < 4; i++) {
      load_lds16(A + arow[i] + k0, As + (w * 4 + i) * 512);
      load_lds16(W + brow[i] + k0, Bs + (w * 4 + i) * 512);
    }
    __syncthreads();
#pragma unroll
    for (int s = 0; s < 2; s++) {
      const int swz = ((s * 4 + qq) ^ (c & 7)) * 8;
      short8 af[4], bf[4];
#pragma unroll
      for (int i = 0; i < 4; i++)
        af[i] = *(const short8*)&As[(mq + i * 16 + c) * 64 + swz];
#pragma unroll
      for (int j = 0; j < 4; j++)
        bf[j] = *(const short8*)&Bs[(nq + j * 16 + c) * 64 + swz];
#pragma unroll
      for (int i = 0; i < 4; i++)
#pragma unroll
        for (int j = 0; j < 4; j++)
          acc[i][j] = __builtin_amdgcn_mfma_f32_16x16x32_bf16(af[i], bf[j], acc[i][j], 0, 0, 0);
    }
  }
  float bj[4] = {0.f, 0.f, 0.f, 0.f};
  if (BIAS) {
#pragma unroll
    for (int j = 0; j < 4; j++) bj[j] = bias[n0 + nq + c + j * 16];
  }
#pragma unroll
  for (int i = 0; i < 4; i++)
#pragma unroll
    for (int r = 0; r < 4; r++) {
      const size_t row = (size_t)(m0 + mq + i * 16 + qq * 4 + r) * NP + n0 + nq + c;
      if (BF16OUT) {
#pragma unroll
        for (int j = 0; j < 4; j++)
          ((u16*)C)[row + j * 16] = f2bf(acc[i][j][r]);
      } else {
#pragma unroll
        for (int j = 0; j < 4; j++)
          ((float*)C)[row + j * 16] = acc[i][j][r] + bj[j];
      }
    }
}

// MFMA attention v5. 1-D grid (768 = 3 blocks/CU), XCD-swizzled (K/VT live in
// the XCD L2 — R7 verified FETCH 172->31 MB). 128 q-rows/block; each wave owns
// 16 q-rows x 2 row-groups x {self, cross} = 4 sets. K/VT double-buffered via
// global_load_lds w=16, ONE barrier per chunk (prefetch in flight across the
// whole compute phase).
// KEY CHANGE vs v4: S is computed TRANSPOSED (A=K-frag, B=Q-frag), so the
// score C-layout is col=q, row=key: each lane holds 4 consecutive keys of one
// q-row, letting the exp'd P tile be written q-major with ONE ds_write_b64
// per 4 values (16 b64 writes/chunk/wave instead of 64 b16 scatters). The P
// read-back (A-frag for PV) is unchanged. K-frags hoisted once per chunk
// (shared by all 4 sets). Row denominators via ones-MFMA; P bf16-truncated.
__global__ __launch_bounds__(256, 3)
void attn_pair_mfma(const u16* __restrict__ qkvx, const u16* __restrict__ qkvy,
                    const u16* __restrict__ VT,
                    u16* __restrict__ sum_x, u16* __restrict__ sum_y)
{
  // 40 KB: K 2x8K | VT 2x8K | P 2K/wave
  __shared__ __align__(16) u16 smem[20480];
  float (*Of)[68] = (float(*)[68])smem;      // epilogue alias (34816 B)

  // XCD-aware decode (perf heuristic only)
  const int blk = blockIdx.x;                // 768 blocks
  const int xcd = blk & 7, slot = blk >> 3;  // 96 slots
  const int bh = (slot >> 4) * 8 + xcd;      // 6 groups x 8 = 48
  const int qt = (slot & 15) >> 1, pair = slot & 1;
  const int b = bh / HH, head = bh % HH;
  const u16* q1 = pair ? qkvy : qkvx;  // self q   (j=1, +scale folded)
  const u16* q2 = pair ? qkvx : qkvy;  // cross qo (j=0, -scale folded)
  const u16* ks = pair ? qkvy : qkvx;  // k (j=2)
  u16* outp = pair ? sum_y : sum_x;

  const int t = threadIdx.x, w = t >> 6, lane = t & 63;
  const int c = lane & 15, qq = lane >> 4;

  // Q B-frags (lane n=c holds q-row c of its 16-row group): 4 sets
  short8 Qf[4][2];
#pragma unroll
  for (int g = 0; g < 2; g++) {
    const int qrow = qt * 128 + g * 64 + w * 16 + c;
    const u16* qs = q1 + (size_t)(b * NN + qrow) * 3072 + CC + head * HD + qq * 8;
    const u16* qc = q2 + (size_t)(b * NN + qrow) * 3072 + head * HD + qq * 8;
    Qf[g * 2][0] = *(const short8*)qs;
    Qf[g * 2][1] = *(const short8*)(qs + 32);
    Qf[g * 2 + 1][0] = *(const short8*)qc;
    Qf[g * 2 + 1][1] = *(const short8*)(qc + 32);
  }

  const u16* kbase = ks + (size_t)(b * NN) * 3072 + 2 * CC + head * HD;
  const u16* vtb = VT + (size_t)(bh * 64) * 1024;

  const int lr = lane >> 3;
  const int sc8 = ((lane & 7) ^ lr) * 8;

  u16* Pw = smem + 16384 + w * 1024;  // one wave-private 16x64 P tile (2 KB)

  short8 ones;
#pragma unroll
  for (int i = 0; i < 8; i++) ones[i] = (short)0x3F80;  // bf16 1.0

  f32x4 O[4][4] = {};  // [set][t4]
  f32x4 L[4] = {};

  const int cx = c & 7;
  const int off0 = (qq ^ cx) * 8;
  const int off1 = ((4 + qq) ^ cx) * 8;

  // double-buffered staging: 4 issues/wave into half `hf`
  auto stage = [&](int c16, int hf) {
#pragma unroll
    for (int i = 0; i < 2; i++) {
      const int r = (2 * w + i) * 8 + lr;
      load_lds16(kbase + (size_t)(c16 * 64 + r) * 3072 + sc8,
                 smem + hf * 4096 + (2 * w + i) * 512);
      load_lds16(vtb + (size_t)r * 1024 + c16 * 64 + sc8,
                 smem + 8192 + hf * 4096 + (2 * w + i) * 512);
    }
  };

  stage(0, 0);
  for (int c16 = 0; c16 < 16; ++c16) {
    __syncthreads();  // chunk c16 landed (in flight during prev compute);
                      // all reads of the other half are done
    if (c16 < 15) stage(c16 + 1, (c16 + 1) & 1);
    const u16* Kc = smem + (c16 & 1) * 4096;
    const u16* Vc = smem + 8192 + (c16 & 1) * 4096;

    // K A-frags hoisted: shared by all 4 sets (self & cross share K)
    short8 kf[8];
#pragma unroll
    for (int t4 = 0; t4 < 4; t4++) {
      const u16* kr = Kc + (16 * t4 + c) * 64;
      kf[2 * t4] = *(const short8*)(kr + off0);
      kf[2 * t4 + 1] = *(const short8*)(kr + off1);
    }

#pragma unroll
    for (int s = 0; s < 4; s++) {
      // S^T = K Q^T : C-layout col=q(=c), row=key(=16*t4+4*qq+r)
#pragma unroll
      for (int t4 = 0; t4 < 4; t4++) {
        f32x4 z = {0.f, 0.f, 0.f, 0.f};
        z = __builtin_amdgcn_mfma_f32_16x16x32_bf16(kf[2 * t4], Qf[s][0], z, 0, 0, 0);
        z = __builtin_amdgcn_mfma_f32_16x16x32_bf16(kf[2 * t4 + 1], Qf[s][1], z, 0, 0, 0);
        // exp2 + truncate + pack 4 consecutive keys -> one b64 write
        unsigned int u0 = __float_as_uint(__ocml_native_exp2_f32(z[0]));
        unsigned int u1 = __float_as_uint(__ocml_native_exp2_f32(z[1]));
        unsigned int u2 = __float_as_uint(__ocml_native_exp2_f32(z[2]));
        unsigned int u3 = __float_as_uint(__ocml_native_exp2_f32(z[3]));
        uint2 pk;
        pk.x = (u0 >> 16) | (u1 & 0xffff0000u);
        pk.y = (u2 >> 16) | (u3 & 0xffff0000u);
        // P[q=c][key] with XOR-chunk swizzle; keys 16*t4+4*qq+0..3
        const int base = c * 64 + (((2 * t4 + (qq >> 1)) ^ cx) * 8) + 4 * (qq & 1);
        *(uint2*)(Pw + base) = pk;
      }
      // P A-frags (wave-private, DS in-order: no barrier) + L + PV
      short8 pa0 = *(const short8*)(Pw + c * 64 + off0);
      short8 pa1 = *(const short8*)(Pw + c * 64 + off1);
      L[s] = __builtin_amdgcn_mfma_f32_16x16x32_bf16(pa0, ones, L[s], 0, 0, 0);
      L[s] = __builtin_amdgcn_mfma_f32_16x16x32_bf16(pa1, ones, L[s], 0, 0, 0);
#pragma unroll
      for (int t4 = 0; t4 < 4; t4++) {
        const u16* vr = Vc + (16 * t4 + c) * 64;
        short8 v0 = *(const short8*)(vr + off0);
        short8 v1 = *(const short8*)(vr + off1);
        O[s][t4] = __builtin_amdgcn_mfma_f32_16x16x32_bf16(pa0, v0, O[s][t4], 0, 0, 0);
        O[s][t4] = __builtin_amdgcn_mfma_f32_16x16x32_bf16(pa1, v1, O[s][t4], 0, 0, 0);
      }
    }
  }

  __syncthreads();  // all waves done with K/VT/P -> realias as Of
#pragma unroll
  for (int g = 0; g < 2; g++) {
    float is[4], ic[4];
#pragma unroll
    for (int r = 0; r < 4; r++) {
      is[r] = 1.0f / L[g * 2][r];
      ic[r] = 1.0f / L[g * 2 + 1][r];
    }
#pragma unroll
    for (int t4 = 0; t4 < 4; t4++)
#pragma unroll
      for (int r = 0; r < 4; r++)
        Of[g * 64 + w * 16 + 4 * qq + r][16 * t4 + c] =
            O[g * 2][t4][r] * is[r] + O[g * 2 + 1][t4][r] * ic[r];
  }
  __syncthreads();
  // out[b, qt*128+row, head*64+d] (bf16, coalesced)
#pragma unroll
  for (int p = 0; p < 8; p++) {
    const int idx = p * 256 + t;
    const int row = idx >> 4, c4 = (idx & 15) * 4;
    float4 v = *(const float4*)&Of[row][c4];
    ushort4 u = {f2bf(v.x), f2bf(v.y), f2bf(v.z), f2bf(v.w)};
    *(ushort4*)(outp + (size_t)(b * NN + qt * 128 + row) * CC + head * HD + c4) = u;
  }
}

extern "C" void kernel_launch(void* const* d_in, const int* in_sizes, int n_in,
                              void* d_out, int out_size, void* d_ws, size_t ws_size,
                              hipStream_t stream)
{
  const float* x      = (const float*)d_in[0];
  const float* y      = (const float*)d_in[1];
  const float* w_qkv  = (const float*)d_in[2];
  const float* w_proj = (const float*)d_in[3];
  const float* b_proj = (const float*)d_in[4];

  // ws layout (75.1 MB used):
  //   qkv_x 25.2 | qkv_y 25.2 | sum_x 6.3 (alias x_bf) | sum_y 6.3 (alias y_bf)
  //   | wq_bf 4.7 | wp_bf 1.2 | VT 6.3
  u16* qkv_x = (u16*)d_ws;
  u16* qkv_y = qkv_x + (size_t)4096 * 3072;
  u16* rest = qkv_y + (size_t)4096 * 3072;
  u16* sum_x = rest;
  u16* sum_y = sum_x + (size_t)4096 * 768;
  u16* x_bf  = rest;                       // aliases sum_x (dead after QKV)
  u16* y_bf  = x_bf + (size_t)4096 * 768;  // aliases sum_y
  u16* wq_bf = y_bf + (size_t)4096 * 768;
  u16* wp_bf = wq_bf + (size_t)3072 * 768;
  u16* VT    = wp_bf + (size_t)768 * 768;
  float* out_x = (float*)d_out;
  float* out_y = out_x + (size_t)4096 * 768;

  // 0) fp32 -> bf16 (w_qkv query rows pre-scaled by ±0.125·log2e)
  cvt_bf16<<<dim3(1536, 4), 256, 0, stream>>>(x, y, w_qkv, w_proj,
                                              x_bf, y_bf, wq_bf, wp_bf);

  // 1) QKV via MFMA: qkv_{x,y} = {x,y}_bf @ wq_bf^T (bf16 out)
  gemm_mfma<3072, true, false><<<dim3(24, 32, 2), 256, 0, stream>>>(
      x_bf, y_bf, wq_bf, nullptr, qkv_x, qkv_y);

  // 1.5) V^T prepass (v always from x), XCD-swizzled
  vtrans<<<dim3(1536), 256, 0, stream>>>(qkv_x, VT);

  // 2) paired MFMA attention -> sum_x, sum_y (bf16), XCD-swizzled 1-D grid
  attn_pair_mfma<<<dim3(768), 256, 0, stream>>>(qkv_x, qkv_y, VT, sum_x, sum_y);

  // 3) out = sum @ wp_bf^T + b_proj (f32, MFMA)
  gemm_mfma<768, false, true><<<dim3(6, 32, 2), 256, 0, stream>>>(
      sum_x, sum_y, wp_bf, b_proj, out_x, out_y);
}

// Round 9
// 214.861 us; speedup vs baseline: 1.1854x; 1.1854x over previous
//
#include <hip/hip_runtime.h>
#include <hip/hip_bf16.h>
#include <stdint.h>

// Problem: B=4, N=1024, C=768, H=12, hd=64.
// out_x = (attn(qx,kx,vx,+) + attn(qyo,kx,vx,-)) @ Wp^T + bp
// out_y = (attn(qy,ky,vx,+) + attn(qxo,ky,vx,-)) @ Wp^T + bp   (vy = vx!)
// qkv[b,n, j*768 + h*64 + d], j in {0:qo, 1:q, 2:k, 3:v}
// NOTE: w_qkv rows j=0 are pre-scaled by -0.125*log2(e), j=1 by +0.125*log2(e)
// in cvt_bf16, so attention scores emerge in the log2 domain with sign folded:
// softmax is exp2(s) directly for BOTH self and cross attends.

#define BB 4
#define NN 1024
#define CC 768
#define HH 12
#define HD 64

typedef unsigned short u16;
typedef short short8 __attribute__((ext_vector_type(8)));
typedef float f32x4 __attribute__((ext_vector_type(4)));

extern "C" __device__ float __ocml_native_exp2_f32(float);

__device__ __forceinline__ u16 f2bf(float f) {
  unsigned int u = __float_as_uint(f);
  return (u16)((u + 0x7fffu + ((u >> 16) & 1u)) >> 16);
}

__device__ __forceinline__ void load_lds16(const u16* g, u16* l) {
  __builtin_amdgcn_global_load_lds((__attribute__((address_space(1))) const void*)g,
                                   (__attribute__((address_space(3))) void*)l, 16, 0, 0);
}

// fp32 -> bf16 conversion: seg 0=x, 1=y, 2=w_qkv (query rows pre-scaled), 3=w_proj
__global__ __launch_bounds__(256)
void cvt_bf16(const float* __restrict__ x, const float* __restrict__ y,
              const float* __restrict__ wq, const float* __restrict__ wp,
              u16* __restrict__ xb, u16* __restrict__ yb,
              u16* __restrict__ wqb, u16* __restrict__ wpb)
{
  const int seg = blockIdx.y;
  const float* src = seg == 0 ? x : (seg == 1 ? y : (seg == 2 ? wq : wp));
  u16* dst = seg == 0 ? xb : (seg == 1 ? yb : (seg == 2 ? wqb : wpb));
  const int n = (seg == 3) ? 768 * 768 : ((seg == 2) ? 3072 * 768 : 4096 * 768);
  const int i = (blockIdx.x * 256 + threadIdx.x) * 8;
  if (i >= n) return;
  float sc = 1.0f;
  if (seg == 2) {
    const int row = i / 768;  // output feature p; j = p/768
    sc = (row < 768) ? -0.18033688f : (row < 1536 ? 0.18033688f : 1.0f);
  }
  float4 a = *(const float4*)(src + i);
  float4 b = *(const float4*)(src + i + 4);
  ushort4 u0 = {f2bf(a.x * sc), f2bf(a.y * sc), f2bf(a.z * sc), f2bf(a.w * sc)};
  ushort4 u1 = {f2bf(b.x * sc), f2bf(b.y * sc), f2bf(b.z * sc), f2bf(b.w * sc)};
  *(ushort4*)(dst + i) = u0;
  *(ushort4*)(dst + i + 4) = u1;
}

// V^T prepass: VT[(bh*64 + d)*1024 + key] = qkv_x[b, key, 3*768 + h*64 + d]
// 1-D grid, XCD-swizzled so producer blocks land on the XCD that consumes VT[bh].
__global__ __launch_bounds__(256)
void vtrans(const u16* __restrict__ qkvx, u16* __restrict__ VT)
{
  const int blk = blockIdx.x;                 // 1536 blocks
  const int xcd = blk & 7, slot = blk >> 3;   // 192 slots
  const int bh = (slot >> 5) * 8 + xcd;       // 6 groups x 8 = 48
  const int kt = slot & 31;                   // 32 key-tiles
  const int b = bh / HH, h = bh % HH;
  const int t = threadIdx.x;
  const int key = kt * 32 + (t >> 3), d0 = (t & 7) * 8;
  uint4 v = *(const uint4*)(qkvx + (size_t)(b * NN + key) * 3072 + 3 * CC + h * HD + d0);
  u16 e[8];
  *(uint4*)e = v;
#pragma unroll
  for (int i = 0; i < 8; i++)
    VT[(size_t)(bh * 64 + d0 + i) * 1024 + key] = e[i];
}

// MFMA GEMM: C[m,p] = A[m,:] . W[p,:] (+bias). 128x128 tile, 4 waves, BK=64.
// global_load_lds width=16 staging + XOR swizzle (chunk ^ row&7).
template<int NP, bool BF16OUT, bool BIAS>
__global__ __launch_bounds__(256)
void gemm_mfma(const u16* __restrict__ A0, const u16* __restrict__ A1,
               const u16* __restrict__ W, const float* __restrict__ bias,
               void* __restrict__ C0, void* __restrict__ C1)
{
  __shared__ u16 As[128 * 64];
  __shared__ u16 Bs[128 * 64];
  const u16* A = blockIdx.z ? A1 : A0;
  void* C = blockIdx.z ? C1 : C0;
  const int m0 = blockIdx.y * 128, n0 = blockIdx.x * 128;
  const int t = threadIdx.x, w = t >> 6, lane = t & 63;
  const int c = lane & 15, qq = lane >> 4;
  const int mq = (w >> 1) * 64, nq = (w & 1) * 64;

  const int lrow = lane >> 3;
  const int lchunk = (lane & 7) ^ lrow;
  size_t arow[4], brow[4];
#pragma unroll
  for (int i = 0; i < 4; i++) {
    const int r = (w * 4 + i) * 8 + lrow;
    arow[i] = (size_t)(m0 + r) * 768 + lchunk * 8;
    brow[i] = (size_t)(n0 + r) * 768 + lchunk * 8;
  }

  f32x4 acc[4][4] = {};
  for (int k0 = 0; k0 < 768; k0 += 64) {
    __syncthreads();
#pragma unroll
    for (int i = 0; i < 4; i++) {
      load_lds16(A + arow[i] + k0, As + (w * 4 + i) * 512);
      load_lds16(W + brow[i] + k0, Bs + (w * 4 + i) * 512);
    }
    __syncthreads();
#pragma unroll
    for (int s = 0; s < 2; s++) {
      const int swz = ((s * 4 + qq) ^ (c & 7)) * 8;
      short8 af[4], bf[4];
#pragma unroll
      for (int i = 0; i < 4; i++)
        af[i] = *(const short8*)&As[(mq + i * 16 + c) * 64 + swz];
#pragma unroll
      for (int j = 0; j < 4; j++)
        bf[j] = *(const short8*)&Bs[(nq + j * 16 + c) * 64 + swz];
#pragma unroll
      for (int i = 0; i < 4; i++)
#pragma unroll
        for (int j = 0; j < 4; j++)
          acc[i][j] = __builtin_amdgcn_mfma_f32_16x16x32_bf16(af[i], bf[j], acc[i][j], 0, 0, 0);
    }
  }
  float bj[4] = {0.f, 0.f, 0.f, 0.f};
  if (BIAS) {
#pragma unroll
    for (int j = 0; j < 4; j++) bj[j] = bias[n0 + nq + c + j * 16];
  }
#pragma unroll
  for (int i = 0; i < 4; i++)
#pragma unroll
    for (int r = 0; r < 4; r++) {
      const size_t row = (size_t)(m0 + mq + i * 16 + qq * 4 + r) * NP + n0 + nq + c;
      if (BF16OUT) {
#pragma unroll
        for (int j = 0; j < 4; j++)
          ((u16*)C)[row + j * 16] = f2bf(acc[i][j][r]);
      } else {
#pragma unroll
        for (int j = 0; j < 4; j++)
          ((float*)C)[row + j * 16] = acc[i][j][r] + bj[j];
      }
    }
}

// MFMA attention v6 — occupancy-first. 1-D grid 1536 (6 blocks/CU dispatched,
// 4 resident: LDS 34.8 KB), XCD-swizzled (32 blocks per (b,head) on one XCD;
// R7 verified FETCH 172->31 MB). 64 q-rows/block; each wave owns 16 q-rows x
// {self, cross}. K/VT staged single-buffered (m97 2-barrier; inter-block
// overlap hides the staging drain at 4 blocks/CU). S computed TRANSPOSED
// (A=K-frag, B=Q-frag) so each lane holds 4 consecutive keys -> exp'd P
// written as ONE b64 per 4 values. P layout: row stride 72 u16 + ADDITIVE
// swizzle (chunk l stored at position (l+6c)&7): bank group (l+7c)&7 is
// bijective in c -> <=2-way (free) for b64 writes AND b128 reads (v5's XOR
// scheme was structurally 4-way -> 3.2M conflict cycles). Row denominators
// via ones-MFMA; P bf16-truncated (common-mode cancels in normalization).
__global__ __launch_bounds__(256, 4)
void attn_pair_mfma(const u16* __restrict__ qkvx, const u16* __restrict__ qkvy,
                    const u16* __restrict__ VT,
                    u16* __restrict__ sum_x, u16* __restrict__ sum_y)
{
  // 34816 B: K 8K | VT 8K | P 4 waves x 2 sets x (16 x 72) u16
  __shared__ __align__(16) u16 smem[17408];
  float (*Of)[68] = (float(*)[68])smem;  // epilogue alias (64x68 f32 = 17408 B)

  // XCD-aware decode (perf heuristic only)
  const int blk = blockIdx.x;                // 1536 blocks
  const int xcd = blk & 7, slot = blk >> 3;  // 192 slots
  const int bh = (slot >> 5) * 8 + xcd;      // 6 groups x 8 = 48
  const int inner = slot & 31;
  const int qt = inner >> 1, pair = inner & 1;
  const int b = bh / HH, head = bh % HH;
  const u16* q1 = pair ? qkvy : qkvx;  // self q   (j=1, +scale folded)
  const u16* q2 = pair ? qkvx : qkvy;  // cross qo (j=0, -scale folded)
  const u16* ks = pair ? qkvy : qkvx;  // k (j=2)
  u16* outp = pair ? sum_y : sum_x;

  const int t = threadIdx.x, w = t >> 6, lane = t & 63;
  const int c = lane & 15, qq = lane >> 4;

  // Q B-frags (lane n=c holds q-row c of the wave's 16-row tile): 2 sets
  short8 Qf[2][2];
  {
    const int qrow = qt * 64 + w * 16 + c;
    const u16* qs = q1 + (size_t)(b * NN + qrow) * 3072 + CC + head * HD + qq * 8;
    const u16* qc = q2 + (size_t)(b * NN + qrow) * 3072 + head * HD + qq * 8;
    Qf[0][0] = *(const short8*)qs;
    Qf[0][1] = *(const short8*)(qs + 32);
    Qf[1][0] = *(const short8*)qc;
    Qf[1][1] = *(const short8*)(qc + 32);
  }

  const u16* kbase = ks + (size_t)(b * NN) * 3072 + 2 * CC + head * HD;
  const u16* vtb = VT + (size_t)(bh * 64) * 1024;

  const int lr = lane >> 3;
  const int sc8 = ((lane & 7) ^ lr) * 8;

  u16* Pw = smem + 8192 + w * 2304;  // 2 tiles of 16x72 u16 per wave

  short8 ones;
#pragma unroll
  for (int i = 0; i < 8; i++) ones[i] = (short)0x3F80;  // bf16 1.0

  f32x4 O[2][4] = {};  // [set][t4]
  f32x4 L[2] = {};

  const int cx = c & 7;
  const int koff0 = (qq ^ cx) * 8;          // K/VT buffers: XOR staging layout
  const int koff1 = ((4 + qq) ^ cx) * 8;
  const int c6 = (6 * c) & 7;               // P: additive swizzle
  const int poff0 = ((qq + c6) & 7) * 8;
  const int poff1 = ((4 + qq + c6) & 7) * 8;

  for (int c16 = 0; c16 < 16; ++c16) {
    __syncthreads();  // all reads of the buffer done before overwrite
#pragma unroll
    for (int i = 0; i < 2; i++) {
      const int r = (2 * w + i) * 8 + lr;
      load_lds16(kbase + (size_t)(c16 * 64 + r) * 3072 + sc8,
                 smem + (2 * w + i) * 512);
      load_lds16(vtb + (size_t)r * 1024 + c16 * 64 + sc8,
                 smem + 4096 + (2 * w + i) * 512);
    }
    __syncthreads();  // staged data visible (vmcnt(0) before barrier)

    // S^T per t4-tile for both sets; exp2 + pack -> one b64 write per set
#pragma unroll
    for (int t4 = 0; t4 < 4; t4++) {
      const u16* kr = smem + (16 * t4 + c) * 64;
      short8 k0 = *(const short8*)(kr + koff0);
      short8 k1 = *(const short8*)(kr + koff1);
      // P position for keys 16t4+4qq+0..3: chunk l = 2t4+(qq>>1)
      const int l = 2 * t4 + (qq >> 1);
      const int base = c * 72 + (((l + c6) & 7) * 8) + 4 * (qq & 1);
#pragma unroll
      for (int s = 0; s < 2; s++) {
        f32x4 z = {0.f, 0.f, 0.f, 0.f};
        z = __builtin_amdgcn_mfma_f32_16x16x32_bf16(k0, Qf[s][0], z, 0, 0, 0);
        z = __builtin_amdgcn_mfma_f32_16x16x32_bf16(k1, Qf[s][1], z, 0, 0, 0);
        unsigned int u0 = __float_as_uint(__ocml_native_exp2_f32(z[0]));
        unsigned int u1 = __float_as_uint(__ocml_native_exp2_f32(z[1]));
        unsigned int u2 = __float_as_uint(__ocml_native_exp2_f32(z[2]));
        unsigned int u3 = __float_as_uint(__ocml_native_exp2_f32(z[3]));
        uint2 pk;
        pk.x = __builtin_amdgcn_perm(u1, u0, 0x07060302u);  // hi(u1)|hi(u0)
        pk.y = __builtin_amdgcn_perm(u3, u2, 0x07060302u);
        *(uint2*)(Pw + s * 1152 + base) = pk;
      }
    }

    // P A-frags (wave-private, DS in-order per wave: no barrier) + L + PV
    short8 pa[2][2];
#pragma unroll
    for (int s = 0; s < 2; s++) {
      const u16* pr = Pw + s * 1152 + c * 72;
      pa[s][0] = *(const short8*)(pr + poff0);
      pa[s][1] = *(const short8*)(pr + poff1);
      L[s] = __builtin_amdgcn_mfma_f32_16x16x32_bf16(pa[s][0], ones, L[s], 0, 0, 0);
      L[s] = __builtin_amdgcn_mfma_f32_16x16x32_bf16(pa[s][1], ones, L[s], 0, 0, 0);
    }
#pragma unroll
    for (int t4 = 0; t4 < 4; t4++) {
      const u16* vr = smem + 4096 + (16 * t4 + c) * 64;
      short8 v0 = *(const short8*)(vr + koff0);
      short8 v1 = *(const short8*)(vr + koff1);
#pragma unroll
      for (int s = 0; s < 2; s++) {
        O[s][t4] = __builtin_amdgcn_mfma_f32_16x16x32_bf16(pa[s][0], v0, O[s][t4], 0, 0, 0);
        O[s][t4] = __builtin_amdgcn_mfma_f32_16x16x32_bf16(pa[s][1], v1, O[s][t4], 0, 0, 0);
      }
    }
  }

  __syncthreads();  // all waves done with K/VT/P -> realias as Of
  float is[4], ic[4];
#pragma unroll
  for (int r = 0; r < 4; r++) {
    is[r] = 1.0f / L[0][r];
    ic[r] = 1.0f / L[1][r];
  }
#pragma unroll
  for (int t4 = 0; t4 < 4; t4++)
#pragma unroll
    for (int r = 0; r < 4; r++)
      Of[w * 16 + 4 * qq + r][16 * t4 + c] =
          O[0][t4][r] * is[r] + O[1][t4][r] * ic[r];
  __syncthreads();
  // out[b, qt*64+row, head*64+d] (bf16, coalesced)
#pragma unroll
  for (int p = 0; p < 4; p++) {
    const int idx = p * 256 + t;
    const int row = idx >> 4, c4 = (idx & 15) * 4;
    float4 v = *(const float4*)&Of[row][c4];
    ushort4 u = {f2bf(v.x), f2bf(v.y), f2bf(v.z), f2bf(v.w)};
    *(ushort4*)(outp + (size_t)(b * NN + qt * 64 + row) * CC + head * HD + c4) = u;
  }
}

extern "C" void kernel_launch(void* const* d_in, const int* in_sizes, int n_in,
                              void* d_out, int out_size, void* d_ws, size_t ws_size,
                              hipStream_t stream)
{
  const float* x      = (const float*)d_in[0];
  const float* y      = (const float*)d_in[1];
  const float* w_qkv  = (const float*)d_in[2];
  const float* w_proj = (const float*)d_in[3];
  const float* b_proj = (const float*)d_in[4];

  // ws layout (75.1 MB used):
  //   qkv_x 25.2 | qkv_y 25.2 | sum_x 6.3 (alias x_bf) | sum_y 6.3 (alias y_bf)
  //   | wq_bf 4.7 | wp_bf 1.2 | VT 6.3
  u16* qkv_x = (u16*)d_ws;
  u16* qkv_y = qkv_x + (size_t)4096 * 3072;
  u16* rest = qkv_y + (size_t)4096 * 3072;
  u16* sum_x = rest;
  u16* sum_y = sum_x + (size_t)4096 * 768;
  u16* x_bf  = rest;                       // aliases sum_x (dead after QKV)
  u16* y_bf  = x_bf + (size_t)4096 * 768;  // aliases sum_y
  u16* wq_bf = y_bf + (size_t)4096 * 768;
  u16* wp_bf = wq_bf + (size_t)3072 * 768;
  u16* VT    = wp_bf + (size_t)768 * 768;
  float* out_x = (float*)d_out;
  float* out_y = out_x + (size_t)4096 * 768;

  // 0) fp32 -> bf16 (w_qkv query rows pre-scaled by ±0.125·log2e)
  cvt_bf16<<<dim3(1536, 4), 256, 0, stream>>>(x, y, w_qkv, w_proj,
                                              x_bf, y_bf, wq_bf, wp_bf);

  // 1) QKV via MFMA: qkv_{x,y} = {x,y}_bf @ wq_bf^T (bf16 out)
  gemm_mfma<3072, true, false><<<dim3(24, 32, 2), 256, 0, stream>>>(
      x_bf, y_bf, wq_bf, nullptr, qkv_x, qkv_y);

  // 1.5) V^T prepass (v always from x), XCD-swizzled
  vtrans<<<dim3(1536), 256, 0, stream>>>(qkv_x, VT);

  // 2) paired MFMA attention -> sum_x, sum_y (bf16), XCD-swizzled 1-D grid
  attn_pair_mfma<<<dim3(1536), 256, 0, stream>>>(qkv_x, qkv_y, VT, sum_x, sum_y);

  // 3) out = sum @ wp_bf^T + b_proj (f32, MFMA)
  gemm_mfma<768, false, true><<<dim3(6, 32, 2), 256, 0, stream>>>(
      sum_x, sum_y, wp_bf, b_proj, out_x, out_y);
}